// Round 1
// baseline (171.697 us; speedup 1.0000x reference)
//
#include <hip/hip_runtime.h>
#include <hip/hip_bf16.h>
#include <stdint.h>

#define C_DIM 256
#define N_DIM 4096
#define B_DIM 4

typedef __attribute__((ext_vector_type(8))) short s16x8;   // 8 bf16
typedef __attribute__((ext_vector_type(4))) short s16x4;   // 4 bf16
typedef __attribute__((ext_vector_type(4))) float f32x4;
typedef __attribute__((ext_vector_type(16))) float f32x16;

static __device__ __forceinline__ short f2bs(float f) {
    __bf16 h = (__bf16)f;                 // RNE f32->bf16
    return __builtin_bit_cast(short, h);
}

// ---------------------------------------------------------------------------
// Kernel 0: transpose+convert x,y -> xT,yT [B][N][C] bf16; convert weights.
// ---------------------------------------------------------------------------
__global__ __launch_bounds__(256)
void prep_kernel(const float* __restrict__ x, const float* __restrict__ y,
                 const float* __restrict__ wq, const float* __restrict__ wk,
                 const float* __restrict__ wv,
                 short* __restrict__ xT, short* __restrict__ yT,
                 short* __restrict__ wb)
{
    int bid = blockIdx.x;
    int t = threadIdx.x;
    if (bid < 2048) {
        const float* src = (bid < 1024) ? x : y;
        short* dst = (bid < 1024) ? xT : yT;
        int id = bid & 1023;
        int ct = id & 3;            // 4 c-tiles of 64
        int nt = (id >> 2) & 63;    // 64 n-tiles of 64
        int b  = id >> 8;           // 4 batches
        int n0 = nt * 64, c0 = ct * 64;
        __shared__ short T[64][66]; // odd dword stride -> conflict-free
        int l = t & 63;
        int wv_ = t >> 6;
        #pragma unroll
        for (int p = 0; p < 16; ++p) {
            int c = wv_ + p * 4;
            float v = src[((size_t)(b * C_DIM + c0 + c)) * N_DIM + n0 + l];
            T[l][c] = f2bs(v);
        }
        __syncthreads();
        #pragma unroll
        for (int p = 0; p < 16; ++p) {
            int n = wv_ + p * 4;
            dst[((size_t)(b * N_DIM + n0 + n)) * C_DIM + c0 + l] = T[n][l];
        }
    } else {
        // weights: 96 blocks x 2048 elems
        int id = bid - 2048;
        const float* w = (id < 32) ? wq : (id < 64) ? wk : wv;
        short* dst = wb + (size_t)(id / 32) * (C_DIM * C_DIM);
        int off = (id & 31) * 2048 + t * 8;
        f32x4 a  = *(const f32x4*)(w + off);
        f32x4 b4 = *(const f32x4*)(w + off + 4);
        s16x8 r;
        r[0]=f2bs(a[0]);  r[1]=f2bs(a[1]);  r[2]=f2bs(a[2]);  r[3]=f2bs(a[3]);
        r[4]=f2bs(b4[0]); r[5]=f2bs(b4[1]); r[6]=f2bs(b4[2]); r[7]=f2bs(b4[3]);
        *(s16x8*)(dst + off) = r;
    }
}

// ---------------------------------------------------------------------------
// Kernel 1: projections. Qb,Kb = [B][N][256]; Vb = [B][256][N].
// Q is pre-scaled by log2(e) so attention softmax can use exp2 directly.
// ---------------------------------------------------------------------------
__global__ __launch_bounds__(256)
void proj_kernel(const short* __restrict__ xT, const short* __restrict__ yT,
                 const short* __restrict__ wb,
                 short* __restrict__ Qb, short* __restrict__ Kb,
                 short* __restrict__ Vb)
{
    int bid = blockIdx.x;              // 3072 = 12 * 64 * 4
    int ot = bid & 3;
    int nt = (bid >> 2) & 63;
    int bp = bid >> 8;                 // 0..11 = b*3 + p
    int b = bp / 3, p = bp % 3;
    int n0 = nt * 64, o0 = ot * 64;
    const short* src = (p == 0) ? xT : yT;
    const short* w = wb + (size_t)p * C_DIM * C_DIM;

    __shared__ __align__(16) short Xs[64][264];

    int t = threadIdx.x;
    const short* srcb = src + (size_t)(b * N_DIM + n0) * C_DIM;
    #pragma unroll
    for (int pas = 0; pas < 8; ++pas) {
        int slot = pas * 256 + t;
        int row = slot >> 5, ck = slot & 31;
        *(s16x8*)&Xs[row][ck * 8] = *(const s16x8*)&srcb[(size_t)row * C_DIM + ck * 8];
    }
    __syncthreads();

    int lane = t & 63;
    int wid = t >> 6;
    int m = lane & 15, q = lane >> 4;
    f32x4 acc[4] = {};

    if (p < 2) {
        #pragma unroll
        for (int kk = 0; kk < 8; ++kk) {
            s16x8 af = *(const s16x8*)&Xs[wid * 16 + m][kk * 32 + q * 8];
            #pragma unroll
            for (int ob = 0; ob < 4; ++ob) {
                s16x8 bf = *(const s16x8*)&w[(size_t)(o0 + ob * 16 + m) * C_DIM + kk * 32 + q * 8];
                acc[ob] = __builtin_amdgcn_mfma_f32_16x16x32_bf16(af, bf, acc[ob], 0, 0, 0);
            }
        }
        float sc = (p == 0) ? 1.4426950408889634f : 1.0f;  // log2(e) for Q
        short* dst = ((p == 0) ? Qb : Kb) + (size_t)b * N_DIM * C_DIM;
        #pragma unroll
        for (int ob = 0; ob < 4; ++ob)
            #pragma unroll
            for (int r = 0; r < 4; ++r) {
                int n = n0 + wid * 16 + q * 4 + r;
                int o = o0 + ob * 16 + m;
                dst[(size_t)n * C_DIM + o] = f2bs(acc[ob][r] * sc);
            }
    } else {
        #pragma unroll
        for (int kk = 0; kk < 8; ++kk) {
            s16x8 af = *(const s16x8*)&w[(size_t)(o0 + wid * 16 + m) * C_DIM + kk * 32 + q * 8];
            #pragma unroll
            for (int nb = 0; nb < 4; ++nb) {
                s16x8 bf = *(const s16x8*)&Xs[nb * 16 + m][kk * 32 + q * 8];
                acc[nb] = __builtin_amdgcn_mfma_f32_16x16x32_bf16(af, bf, acc[nb], 0, 0, 0);
            }
        }
        short* dst = Vb + (size_t)b * C_DIM * N_DIM;
        #pragma unroll
        for (int nb = 0; nb < 4; ++nb)
            #pragma unroll
            for (int r = 0; r < 4; ++r) {
                int o = o0 + wid * 16 + q * 4 + r;
                int n = n0 + nb * 16 + m;
                dst[(size_t)o * N_DIM + n] = f2bs(acc[nb][r]);
            }
    }
}

// ---------------------------------------------------------------------------
// Kernel 2: flash attention + epilogue. Symmetric 8-wave design, KVBLK=128.
//
// Wave w = (ib = w>>2, jb = w&3, cbase = w*32):
//   QK: S^T[jb-32k][ib-32q] = mfma(A=K rows, B=Q cols), 16 MFMAs in two
//       independent accumulator chains (ILP 2). In-lane 16-max + xor32 ->
//       mpartT[q][jb].
//   PV: O^T[cbase-strip 32][all 64 q] = 2 acc chains x 8 kc = 16 MFMAs.
// Every SIMD carries 2 waves x 32 MFMAs per jt in both compute phases.
// Single-buffered K/V with T14 staging split: K issued in A / written in B;
// V issued in C / written in next A. 3 barriers per 128 keys.
// ---------------------------------------------------------------------------
__global__ __launch_bounds__(512, 2)
void attn_kernel(const short* __restrict__ Qb, const short* __restrict__ Kb,
                 const short* __restrict__ Vb, const float* __restrict__ x,
                 const float* __restrict__ gamma, float* __restrict__ out)
{
    int bid0 = blockIdx.x;
    int bid = (bid0 & 7) * 32 + (bid0 >> 3);   // XCD swizzle
    int b = bid >> 6, it = bid & 63;
    int i0 = it * 64;

    int t = threadIdx.x;
    int w = t >> 6;
    int lane = t & 63;
    int il = lane & 31;
    int hi = lane >> 5;

    int ib = w >> 2;        // query half (0/1)
    int jb = w & 3;         // key quarter (0..3)
    int cbase = w * 32;     // PV channel strip

    __shared__ __align__(16) short Ks[128][264];   // 67,584 B (stride 132 dw == 4 mod 32)
    __shared__ __align__(16) short Vs[256][136];   // 69,632 B (stride  68 dw == 4 mod 32)
    __shared__ __align__(16) short Ps[64][136];    // 17,408 B
    __shared__ float mpartT[64][4];                // per-query jb-max partials
    __shared__ float spartT[64][4];                // per-query jb-sum partials

    const short* Qp = Qb + (size_t)b * N_DIM * C_DIM;
    const short* Kp = Kb + (size_t)b * N_DIM * C_DIM;
    const short* Vp = Vb + (size_t)b * C_DIM * N_DIM;

    // staging maps: K tile 128x256 (8 chunks/thread), V tile 256x128 (8 chunks)
    int krow = t >> 5, kcol = (t & 31) * 8;    // K row = p*16 + krow
    int vrow = t >> 4, vcol = (t & 15) * 8;    // V row = p*32 + vrow

    // Q fragments: B[k=c][col=q], lane holds q = ib*32+il, k = kk*16+hi*8+e
    s16x8 qf[16];
    {
        const short* qrow = Qp + (size_t)(i0 + ib * 32 + il) * C_DIM + hi * 8;
        #pragma unroll
        for (int kk = 0; kk < 16; ++kk)
            qf[kk] = *(const s16x8*)&qrow[kk * 16];
    }

    // prologue: stage tile 0
    {
        s16x8 kr[8], vr[8];
        #pragma unroll
        for (int p = 0; p < 8; ++p)
            kr[p] = *(const s16x8*)&Kp[(size_t)(p * 16 + krow) * C_DIM + kcol];
        #pragma unroll
        for (int p = 0; p < 8; ++p)
            vr[p] = *(const s16x8*)&Vp[(size_t)(p * 32 + vrow) * N_DIM + vcol];
        #pragma unroll
        for (int p = 0; p < 8; ++p)
            *(s16x8*)&Ks[p * 16 + krow][kcol] = kr[p];
        #pragma unroll
        for (int p = 0; p < 8; ++p)
            *(s16x8*)&Vs[p * 32 + vrow][vcol] = vr[p];
    }
    __syncthreads();

    f32x16 acc0 = {}, acc1 = {};
    float mrunA = -3e38f, mrunB = -3e38f;
    float srunA = 0.f, srunB = 0.f;
    s16x8 vreg[8];   // V for NEXT tile: loaded in phase C, written next phase A

    for (int jt = 0; jt < 32; ++jt) {
        bool pf = (jt < 31);
        int j1 = (jt + 1) * 128;

        // ---- Phase A: V-write (prev staged), issue K-next, QK MFMA, max ----
        if (jt > 0) {
            #pragma unroll
            for (int p = 0; p < 8; ++p)
                *(s16x8*)&Vs[p * 32 + vrow][vcol] = vreg[p];
        }
        s16x8 kreg[8];
        if (pf) {
            const short* kg = Kp + (size_t)j1 * C_DIM;
            #pragma unroll
            for (int p = 0; p < 8; ++p)
                kreg[p] = *(const s16x8*)&kg[(size_t)(p * 16 + krow) * C_DIM + kcol];
        }
        f32x16 sv0 = {}, sv1 = {};
        __builtin_amdgcn_s_setprio(1);
        #pragma unroll
        for (int kk = 0; kk < 16; kk += 2) {
            s16x8 a0 = *(const s16x8*)&Ks[jb * 32 + il][kk * 16 + hi * 8];
            sv0 = __builtin_amdgcn_mfma_f32_32x32x16_bf16(a0, qf[kk], sv0, 0, 0, 0);
            s16x8 a1 = *(const s16x8*)&Ks[jb * 32 + il][(kk + 1) * 16 + hi * 8];
            sv1 = __builtin_amdgcn_mfma_f32_32x32x16_bf16(a1, qf[kk + 1], sv1, 0, 0, 0);
        }
        __builtin_amdgcn_s_setprio(0);
        f32x16 sv;
        #pragma unroll
        for (int r = 0; r < 16; ++r) sv[r] = sv0[r] + sv1[r];
        float tmax = sv[0];
        #pragma unroll
        for (int r = 1; r < 16; ++r) tmax = fmaxf(tmax, sv[r]);
        tmax = fmaxf(tmax, __shfl_xor(tmax, 32, 64));
        if (hi == 0) mpartT[ib * 32 + il][jb] = tmax;
        __syncthreads();   // bar1: mpart ready; Ks reads + Vs writes done

        // ---- Phase B: K-write, online-softmax bookkeeping, exp, P write ----
        if (pf) {
            #pragma unroll
            for (int p = 0; p < 8; ++p)
                *(s16x8*)&Ks[p * 16 + krow][kcol] = kreg[p];
        }
        f32x4 mpA = *(const f32x4*)&mpartT[il][0];
        f32x4 mpB = *(const f32x4*)&mpartT[32 + il][0];
        float mnewA = fmaxf(mrunA, fmaxf(fmaxf(mpA[0], mpA[1]), fmaxf(mpA[2], mpA[3])));
        float mnewB = fmaxf(mrunB, fmaxf(fmaxf(mpB[0], mpB[1]), fmaxf(mpB[2], mpB[3])));
        float alphaA = exp2f(mrunA - mnewA);
        float alphaB = exp2f(mrunB - mnewB);
        mrunA = mnewA; mrunB = mnewB;
        if (__any(alphaA != 1.f)) {          // T13: skip rescale if max unchanged
            #pragma unroll
            for (int r = 0; r < 16; ++r) acc0[r] *= alphaA;
        }
        if (__any(alphaB != 1.f)) {
            #pragma unroll
            for (int r = 0; r < 16; ++r) acc1[r] *= alphaB;
        }
        float mown = ib ? mnewB : mnewA;
        float ts = 0.f;
        #pragma unroll
        for (int r = 0; r < 16; ++r) {
            float pe = exp2f(sv[r] - mown);   // Q pre-scaled by log2(e)
            sv[r] = pe;
            ts += pe;
        }
        ts += __shfl_xor(ts, 32, 64);
        if (hi == 0) spartT[ib * 32 + il][jb] = ts;
        // P rows j = jb*32 + 8g + 4hi + (0..3), col q = ib*32+il -> Ps[q][j]
        #pragma unroll
        for (int g = 0; g < 4; ++g) {
            s16x4 pv;
            pv[0] = f2bs(sv[4 * g + 0]); pv[1] = f2bs(sv[4 * g + 1]);
            pv[2] = f2bs(sv[4 * g + 2]); pv[3] = f2bs(sv[4 * g + 3]);
            *(s16x4*)&Ps[ib * 32 + il][jb * 32 + g * 8 + hi * 4] = pv;
        }
        __syncthreads();   // bar2: Ps + spart + Ks(next) staged

        // ---- Phase C: srun update, issue V-next, PV MFMA -------------------
        f32x4 spA = *(const f32x4*)&spartT[il][0];
        f32x4 spB = *(const f32x4*)&spartT[32 + il][0];
        srunA = srunA * alphaA + (spA[0] + spA[1]) + (spA[2] + spA[3]);
        srunB = srunB * alphaB + (spB[0] + spB[1]) + (spB[2] + spB[3]);
        if (pf) {
            const short* vg = Vp + j1;
            #pragma unroll
            for (int p = 0; p < 8; ++p)
                vreg[p] = *(const s16x8*)&vg[(size_t)(p * 32 + vrow) * N_DIM + vcol];
        }
        __builtin_amdgcn_s_setprio(1);
        #pragma unroll
        for (int kc = 0; kc < 8; ++kc) {
            s16x8 af = *(const s16x8*)&Vs[cbase + il][kc * 16 + hi * 8];
            s16x8 b0 = *(const s16x8*)&Ps[il][kc * 16 + hi * 8];
            acc0 = __builtin_amdgcn_mfma_f32_32x32x16_bf16(af, b0, acc0, 0, 0, 0);
            s16x8 b1 = *(const s16x8*)&Ps[32 + il][kc * 16 + hi * 8];
            acc1 = __builtin_amdgcn_mfma_f32_32x32x16_bf16(af, b1, acc1, 0, 0, 0);
        }
        __builtin_amdgcn_s_setprio(0);
        __syncthreads();   // bar3: Vs + Ps reads done before next overwrite
    }

    // epilogue: O^T layout -> out[b][c][i], residual + gamma scale
    float g = gamma[0];
    float invA = 1.f / srunA;
    float invB = 1.f / srunB;
    #pragma unroll
    for (int r = 0; r < 16; ++r) {
        int c = cbase + (r & 3) + 8 * (r >> 2) + 4 * hi;
        size_t idxA = ((size_t)(b * C_DIM + c)) * N_DIM + i0 + il;
        out[idxA] = g * acc0[r] * invA + x[idxA];
        size_t idxB = idxA + 32;
        out[idxB] = g * acc1[r] * invB + x[idxB];
    }
}

// ---------------------------------------------------------------------------
extern "C" void kernel_launch(void* const* d_in, const int* in_sizes, int n_in,
                              void* d_out, int out_size, void* d_ws, size_t ws_size,
                              hipStream_t stream) {
    const float* x  = (const float*)d_in[0];
    const float* y  = (const float*)d_in[1];
    const float* wq = (const float*)d_in[2];
    const float* wk = (const float*)d_in[3];
    const float* wv = (const float*)d_in[4];
    const float* gm = (const float*)d_in[5];
    float* out = (float*)d_out;

    char* ws = (char*)d_ws;
    const size_t SZ = (size_t)B_DIM * N_DIM * C_DIM * sizeof(short); // 8 MB
    short* xT = (short*)(ws);
    short* yT = (short*)(ws + SZ);
    short* Qb = (short*)(ws + 2 * SZ);
    short* Kb = (short*)(ws + 3 * SZ);
    short* Vb = (short*)(ws + 4 * SZ);
    short* wb = (short*)(ws + 5 * SZ); // 384 KB

    prep_kernel<<<dim3(2048 + 96), dim3(256), 0, stream>>>(x, y, wq, wk, wv, xT, yT, wb);
    proj_kernel<<<dim3(3072), dim3(256), 0, stream>>>(xT, yT, wb, Qb, Kb, Vb);
    attn_kernel<<<dim3(256), dim3(512), 0, stream>>>(Qb, Kb, Vb, x, gm, out);
}